// Round 2
// baseline (270.624 us; speedup 1.0000x reference)
//
#include <hip/hip_runtime.h>
#include <math.h>

typedef float f32x4 __attribute__((ext_vector_type(4)));
typedef short s16x8 __attribute__((ext_vector_type(8)));

#define L2E 1.4426950408889634f
#define C2L2E 2.885390081777927f  // 2*log2(e)

// ---------------- K0: W -> bf16 hi/lo in per-lane B-fragment order ----------
// t = (et*4+kstep)*512 + lane*8 + q  <->  e=(lane&15)+16*et, k=32*kstep+8*(lane>>4)+q
__global__ void k0_prep(const float* __restrict__ W,
                        unsigned short* __restrict__ gBh,
                        unsigned short* __restrict__ gBl) {
  int t = blockIdx.x * 256 + threadIdx.x;  // 0..16383
  int slot = t >> 3, q = t & 7;
  int lane = slot & 63, fs = slot >> 6;
  int kstep = fs & 3, et = fs >> 2;
  int e = (lane & 15) + 16 * et;
  int k = 32 * kstep + 8 * (lane >> 4) + q;
  float w = W[k * 128 + e];
  unsigned u = __float_as_uint(w);
  unsigned hb = (u + 0x7fffu + ((u >> 16) & 1u)) >> 16;  // RNE hi
  float r = w - __uint_as_float(hb << 16);               // exact
  unsigned ul = __float_as_uint(r);
  unsigned lb = (ul + 0x7fffu + ((ul >> 16) & 1u)) >> 16;  // RNE lo
  gBh[t] = (unsigned short)hb;
  gBl[t] = (unsigned short)lb;
}

// ---------------- K1: logits[b][j][i] = v^T tanh(W^T (x_i*x_j) + b) ----------
// block = 16 j x 8 i; wave w owns i_local {2w, 2w+1}. bf16x3 MFMA.
// B-frags come straight from global (pre-swizzled, identical across waves -> L1).
__global__ __launch_bounds__(256, 3) void k1_logits(
    const float* __restrict__ x, const unsigned short* __restrict__ gBh,
    const unsigned short* __restrict__ gBl, const float* __restrict__ apb,
    const float* __restrict__ av, float* __restrict__ Lg) {
  __shared__ __align__(16) float sXj[16 * 132];
  __shared__ __align__(16) float sXi[8 * 132];

  const int tid = threadIdx.x;
  const int b = blockIdx.z, i0 = blockIdx.y * 8, j0 = blockIdx.x * 16;

  {  // stage x rows (pad 132: 16B-aligned rows, <=2-way bank alias)
    const float4* xj = (const float4*)(x + ((size_t)(b * 256 + j0)) * 128);
#pragma unroll
    for (int r = 0; r < 2; ++r) {
      int v = tid + 256 * r;
      *(float4*)&sXj[(v >> 5) * 132 + (v & 31) * 4] = xj[v];
    }
    const float4* xi = (const float4*)(x + ((size_t)(b * 256 + i0)) * 128);
    *(float4*)&sXi[(tid >> 5) * 132 + (tid & 31) * 4] = xi[tid];
  }
  __syncthreads();

  const int lane = tid & 63;
  const int w = tid >> 6;
  const int quad = lane >> 4;
  const int col = lane & 15;

  float vw[8];
  f32x4 acc[2][8];
#pragma unroll
  for (int et = 0; et < 8; ++et) {
    float bi = apb[col + 16 * et];  // fold att_proj_b into acc init
    vw[et] = av[col + 16 * et];
    acc[0][et] = (f32x4){bi, bi, bi, bi};
    acc[1][et] = (f32x4){bi, bi, bi, bi};
  }

  const unsigned short* BhL = gBh + (size_t)lane * 8;
  const unsigned short* BlL = gBl + (size_t)lane * 8;

#pragma unroll
  for (int kstep = 0; kstep < 4; ++kstep) {
    const int k0 = kstep * 32 + quad * 8;
    float4 xj0 = *(const float4*)&sXj[col * 132 + k0];
    float4 xj1 = *(const float4*)&sXj[col * 132 + k0 + 4];
    s16x8 Ah[2], Al[2];
#pragma unroll
    for (int mt = 0; mt < 2; ++mt) {
      const float* xr = &sXi[(2 * w + mt) * 132 + k0];
      float4 xi0 = *(const float4*)xr;
      float4 xi1 = *(const float4*)(xr + 4);
      float pv[8];
      pv[0] = xi0.x * xj0.x; pv[1] = xi0.y * xj0.y;
      pv[2] = xi0.z * xj0.z; pv[3] = xi0.w * xj0.w;
      pv[4] = xi1.x * xj1.x; pv[5] = xi1.y * xj1.y;
      pv[6] = xi1.z * xj1.z; pv[7] = xi1.w * xj1.w;
#pragma unroll
      for (int q = 0; q < 8; ++q) {
        unsigned u = __float_as_uint(pv[q]);
        float r = pv[q] - __uint_as_float(u & 0xffff0000u);  // exact residual
        Ah[mt][q] = (short)(u >> 16);                        // hi = trunc
        Al[mt][q] = (short)((__float_as_uint(r) + 0x8000u) >> 16);
      }
    }
#pragma unroll
    for (int et = 0; et < 8; ++et) {
      const int fs = (et * 4 + kstep) * 512;  // shorts per frag-slot block
      s16x8 bh = *(const s16x8*)(BhL + fs);
      s16x8 bl = *(const s16x8*)(BlL + fs);
#pragma unroll
      for (int mt = 0; mt < 2; ++mt) {
        acc[mt][et] = __builtin_amdgcn_mfma_f32_16x16x32_bf16(Ah[mt], bh, acc[mt][et], 0, 0, 0);
        acc[mt][et] = __builtin_amdgcn_mfma_f32_16x16x32_bf16(Al[mt], bh, acc[mt][et], 0, 0, 0);
        acc[mt][et] = __builtin_amdgcn_mfma_f32_16x16x32_bf16(Ah[mt], bl, acc[mt][et], 0, 0, 0);
      }
    }
  }

  // epilogue: tanh(y) = 1 - 2/(exp2(2*log2e*y)+1); inf/0 limits exact, no clamp
#pragma unroll
  for (int mt = 0; mt < 2; ++mt) {
    float ls[4] = {0.f, 0.f, 0.f, 0.f};
#pragma unroll
    for (int et = 0; et < 8; ++et) {
#pragma unroll
      for (int r = 0; r < 4; ++r) {
        float e2 = __builtin_amdgcn_exp2f(acc[mt][et][r] * C2L2E);
        float t = 1.0f - 2.0f * __builtin_amdgcn_rcpf(e2 + 1.0f);
        ls[r] += t * vw[et];
      }
    }
#pragma unroll
    for (int m = 1; m < 16; m <<= 1) {
      ls[0] += __shfl_xor(ls[0], m);
      ls[1] += __shfl_xor(ls[1], m);
      ls[2] += __shfl_xor(ls[2], m);
      ls[3] += __shfl_xor(ls[3], m);
    }
    if (col < 4) {
      float ov = (col == 0) ? ls[0] : (col == 1) ? ls[1] : (col == 2) ? ls[2] : ls[3];
      Lg[((size_t)(b * 256 + j0 + quad * 4 + col)) * 256 + i0 + 2 * w + mt] = ov;
    }
  }
}

// ---------------- K2: softmax over i (rows of Lg[b][j][i]), in place --------
__global__ void k2_softmax(float* __restrict__ Lg) {
  const int w = threadIdx.x >> 6, lane = threadIdx.x & 63;
  const int row = blockIdx.x * 4 + w;
  float4* p = (float4*)(Lg + (size_t)row * 256);
  float4 v = p[lane];
  float m = fmaxf(fmaxf(v.x, v.y), fmaxf(v.z, v.w));
#pragma unroll
  for (int mask = 1; mask < 64; mask <<= 1) m = fmaxf(m, __shfl_xor(m, mask));
  v.x = __builtin_amdgcn_exp2f((v.x - m) * L2E);
  v.y = __builtin_amdgcn_exp2f((v.y - m) * L2E);
  v.z = __builtin_amdgcn_exp2f((v.z - m) * L2E);
  v.w = __builtin_amdgcn_exp2f((v.w - m) * L2E);
  float s = v.x + v.y + v.z + v.w;
#pragma unroll
  for (int mask = 1; mask < 64; mask <<= 1) s += __shfl_xor(s, mask);
  float inv = 1.0f / s;
  v.x *= inv; v.y *= inv; v.z *= inv; v.w *= inv;
  p[lane] = v;
}

// ---------------- K34: agg (fp32, LDS) then h = selu(BN(...)), fp64 acc -----
__global__ void k34_aggh(const float* __restrict__ Lg, const float* __restrict__ x,
                         const float* __restrict__ pwa, const float* __restrict__ pwoa,
                         const float* __restrict__ pwab, const float* __restrict__ pwob,
                         const float* __restrict__ gam, const float* __restrict__ bet,
                         const float* __restrict__ mea, const float* __restrict__ varr,
                         float* __restrict__ h) {
  const int b = blockIdx.y, i0 = blockIdx.x * 16;
  const int tid = threadIdx.x;
  const int il = tid >> 4, d0 = (tid & 15) * 8;
  __shared__ float satt[16][17];
  __shared__ float sxj[2048];
  __shared__ float sa[2048];   // agg
  __shared__ float sxi[2048];  // x i-rows

  const float4* xs = (const float4*)(x + ((size_t)(b * 256 + i0)) * 128);
  ((float4*)sxi)[tid] = xs[tid];
  ((float4*)sxi)[tid + 256] = xs[tid + 256];

  float acc[8] = {0.f, 0.f, 0.f, 0.f, 0.f, 0.f, 0.f, 0.f};
  for (int jj = 0; jj < 256; jj += 16) {
    __syncthreads();
    satt[tid >> 4][tid & 15] =
        Lg[((size_t)(b * 256 + jj + (tid >> 4))) * 256 + i0 + (tid & 15)];
    const float4* xsrc = (const float4*)(x + ((size_t)(b * 256 + jj)) * 128);
    ((float4*)sxj)[tid] = xsrc[tid];
    ((float4*)sxj)[tid + 256] = xsrc[tid + 256];
    __syncthreads();
#pragma unroll
    for (int jl = 0; jl < 16; ++jl) {
      float a = satt[jl][il];
      const float* xr = &sxj[jl * 128 + d0];
#pragma unroll
      for (int q = 0; q < 8; ++q) acc[q] += a * xr[q];
    }
  }
  __syncthreads();
#pragma unroll
  for (int q = 0; q < 8; ++q) sa[il * 128 + d0 + q] = acc[q];
  __syncthreads();

  // fp64 h-GEMM; weights read from global — same addr across il-groups -> L1
  double z[8] = {0, 0, 0, 0, 0, 0, 0, 0};
  for (int k = 0; k < 128; ++k) {
    double a = (double)sa[il * 128 + k];
    const float4* wr = (const float4*)(pwa + k * 128 + d0);
    float4 w0 = wr[0], w1 = wr[1];
    z[0] += a * (double)w0.x; z[1] += a * (double)w0.y;
    z[2] += a * (double)w0.z; z[3] += a * (double)w0.w;
    z[4] += a * (double)w1.x; z[5] += a * (double)w1.y;
    z[6] += a * (double)w1.z; z[7] += a * (double)w1.w;
  }
  for (int k = 0; k < 128; ++k) {
    double a = (double)sxi[il * 128 + k];
    const float4* wr = (const float4*)(pwoa + k * 128 + d0);
    float4 w0 = wr[0], w1 = wr[1];
    z[0] += a * (double)w0.x; z[1] += a * (double)w0.y;
    z[2] += a * (double)w0.z; z[3] += a * (double)w0.w;
    z[4] += a * (double)w1.x; z[5] += a * (double)w1.y;
    z[6] += a * (double)w1.z; z[7] += a * (double)w1.w;
  }
  float* dst = h + ((size_t)(b * 256 + i0 + il)) * 128 + d0;
#pragma unroll
  for (int q = 0; q < 8; ++q) {
    int d = d0 + q;
    double hv = z[q] + (double)pwab[d] + (double)pwob[d];
    double bn = (hv - (double)mea[d]) * (1.0 / sqrt((double)varr[d] + 1e-5)) *
                    (double)gam[d] +
                (double)bet[d];
    float bf = (float)bn;
    float se = bf > 0.f ? 1.0507009873554805f * bf
                        : 1.7580993408473766f *
                              (__builtin_amdgcn_exp2f(bf * L2E) - 1.0f);
    dst[q] = se;
  }
}

// ---------------- K5: scores (fp64), stable top-128, gather h*score ---------
__global__ void k5_topk(const float* __restrict__ h, const float* __restrict__ plw,
                        const float* __restrict__ plb, float* __restrict__ out) {
  const int b = blockIdx.x, t = threadIdx.x;
  __shared__ float sc[256];
  __shared__ int sel[128];
  const float* hr = h + ((size_t)(b * 256 + t)) * 128;
  double z = 0.0;
  for (int k = 0; k < 128; ++k) z += (double)hr[k] * (double)plw[k];
  z += (double)plb[0];
  sc[t] = (float)(1.0 / (1.0 + exp(-z)));
  __syncthreads();
  const float st = sc[t];
  int rank = 0;
  for (int m = 0; m < 256; ++m) {
    float sm = sc[m];
    rank += (sm > st) || (sm == st && m < t);  // stable descending
  }
  if (rank < 128) sel[rank] = t;
  __syncthreads();
  const float4* h4 = (const float4*)(h + (size_t)b * 256 * 128);
  float4* o4 = (float4*)(out + (size_t)b * 128 * 128);
#pragma unroll
  for (int r = 0; r < 16; ++r) {
    int v = t + 256 * r;
    int row = v >> 5, q = v & 31;
    int src = sel[row];
    float ss = sc[src];
    float4 hv = h4[src * 32 + q];
    float4 ov;
    ov.x = hv.x * ss; ov.y = hv.y * ss; ov.z = hv.z * ss; ov.w = hv.w * ss;
    o4[row * 32 + q] = ov;
  }
}

extern "C" void kernel_launch(void* const* d_in, const int* in_sizes, int n_in,
                              void* d_out, int out_size, void* d_ws, size_t ws_size,
                              hipStream_t stream) {
  const float* x    = (const float*)d_in[0];
  const float* apw  = (const float*)d_in[1];
  const float* apb  = (const float*)d_in[2];
  const float* av   = (const float*)d_in[3];
  const float* pwa  = (const float*)d_in[4];
  const float* pwab = (const float*)d_in[5];
  const float* pwoa = (const float*)d_in[6];
  const float* pwob = (const float*)d_in[7];
  const float* gam  = (const float*)d_in[8];
  const float* bet  = (const float*)d_in[9];
  const float* mea  = (const float*)d_in[10];
  const float* varr = (const float*)d_in[11];
  const float* plw  = (const float*)d_in[12];
  const float* plb  = (const float*)d_in[13];
  float* out = (float*)d_out;

  unsigned short* gBh = (unsigned short*)d_ws;
  unsigned short* gBl = gBh + 16384;
  float* Lg = (float*)((char*)d_ws + 65536);
  float* hb = Lg + (size_t)16 * 256 * 256;

  k0_prep<<<64, 256, 0, stream>>>(apw, gBh, gBl);
  k1_logits<<<dim3(16, 32, 16), 256, 0, stream>>>(x, gBh, gBl, apb, av, Lg);
  k2_softmax<<<1024, 256, 0, stream>>>(Lg);
  k34_aggh<<<dim3(16, 16), 256, 0, stream>>>(Lg, x, pwa, pwoa, pwab, pwob, gam,
                                             bet, mea, varr, hb);
  k5_topk<<<16, 256, 0, stream>>>(hb, plw, plb, out);
}